// Round 7
// baseline (801.782 us; speedup 1.0000x reference)
//
#include <hip/hip_runtime.h>
#include <hip/hip_cooperative_groups.h>

namespace cg = cooperative_groups;

#define B 64
#define SIZE 2048
#define L 16
#define A 64
#define HID 256
#define R_N 65536
#define XCOLS (SIZE + L)
#define ST_ELEMS ((L + 1) * SIZE * B)
#define RPB 128
#define RPC 256

typedef short bf16x8 __attribute__((ext_vector_type(8)));
typedef float f32x4 __attribute__((ext_vector_type(4)));

__device__ __forceinline__ unsigned short f2bf(float f) {
    unsigned int u = __float_as_uint(f);
    unsigned int r = (u + 0x7fffu + ((u >> 16) & 1u)) >> 16;
    return (unsigned short)r;
}

// ---------- init: zero ST[1..16], ST[0] = x^T, zero hist/cursor ----------
__global__ __launch_bounds__(256) void k_init(const int* __restrict__ x,
                                              float* __restrict__ ST,
                                              int* __restrict__ hist,
                                              int* __restrict__ cursor) {
    int tid = threadIdx.x;
    float4* z = (float4*)(ST + (size_t)SIZE * B);
    int total4 = L * SIZE * B / 4;
    float4 zv = {0.f, 0.f, 0.f, 0.f};
    for (int i = blockIdx.x * 256 + tid; i < total4; i += gridDim.x * 256)
        z[i] = zv;
    if (blockIdx.x == 32) {
        for (int i = tid; i < 2048; i += 256) {
            hist[i] = 0;
            cursor[i] = 0;
        }
    }
    if (blockIdx.x < 32) {
        __shared__ float tile[64][65];
        int s0 = blockIdx.x * 64;
        for (int i = tid; i < 4096; i += 256) {
            int b = i >> 6, sc = i & 63;
            tile[b][sc] = (float)x[b * XCOLS + s0 + sc];
        }
        __syncthreads();
        for (int i = tid; i < 4096; i += 256) {
            int si = i >> 6, b = i & 63;
            ST[(size_t)(s0 + si) * B + b] = tile[b][si];
        }
    }
}

// ---------- histogram of rel_obj ----------
__global__ __launch_bounds__(256) void k_hist(const int* __restrict__ rel_obj,
                                              int* __restrict__ hist) {
    for (int i = blockIdx.x * 256 + threadIdx.x; i < R_N; i += 64 * 256)
        atomicAdd(&hist[rel_obj[i]], 1);
}

// ---------- block 0: exclusive scan; block 1: w2t = bf16(w2^T) ----------
__global__ __launch_bounds__(256) void k_scan(const int* __restrict__ hist,
                                              int* __restrict__ off,
                                              const float* __restrict__ w2,
                                              unsigned short* __restrict__ w2t) {
    int tid = threadIdx.x;
    if (blockIdx.x == 1) {
        for (int i = tid; i < 64 * 256; i += 256) {
            int c = i >> 8, k = i & 255;
            w2t[i] = f2bf(w2[(size_t)k * 64 + c]);
        }
        return;
    }
    __shared__ int tsum[256];
    int v[8], pre[8];
    int s = 0;
#pragma unroll
    for (int i = 0; i < 8; i++) {
        v[i] = hist[tid * 8 + i];
        pre[i] = s;
        s += v[i];
    }
    tsum[tid] = s;
    __syncthreads();
    for (int ofs = 1; ofs < 256; ofs <<= 1) {
        int t = 0;
        if (tid >= ofs) t = tsum[tid - ofs];
        __syncthreads();
        tsum[tid] += t;
        __syncthreads();
    }
    int ebase = tsum[tid] - s;
#pragma unroll
    for (int i = 0; i < 8; i++) off[tid * 8 + i] = ebase + pre[i];
    if (tid == 255) off[2048] = tsum[255];
}

// ---------- scatter sorted positions ----------
__global__ __launch_bounds__(256) void k_scatter(const int* __restrict__ rel_subj,
                                                 const int* __restrict__ rel_obj,
                                                 const int* __restrict__ off,
                                                 int* __restrict__ cursor,
                                                 int* __restrict__ subjS,
                                                 int* __restrict__ objS) {
    for (int r = blockIdx.x * 256 + threadIdx.x; r < R_N; r += 64 * 256) {
        int obj = rel_obj[r];
        int pos = off[obj] + atomicAdd(&cursor[obj], 1);
        subjS[pos] = rel_subj[r];
        objS[pos] = obj;
    }
}

// ---------- P1 = emb @ W1a, P2 = emb @ W1b ----------
__global__ __launch_bounds__(256) void k_p12(const float* __restrict__ state_emb,
                                             const float* __restrict__ w1,
                                             float* __restrict__ P1,
                                             float* __restrict__ P2) {
    __shared__ float emb8[8][64];
    int tid = threadIdx.x;
    int sbase = blockIdx.x * 8;
    for (int i = tid; i < 512; i += 256)
        emb8[i >> 6][i & 63] = state_emb[(size_t)(sbase + (i >> 6)) * 64 + (i & 63)];
    __syncthreads();
    float acc1[8], acc2[8];
#pragma unroll
    for (int s = 0; s < 8; s++) { acc1[s] = 0.f; acc2[s] = 0.f; }
    for (int k = 0; k < 64; k++) {
        float wa = w1[(size_t)k * HID + tid];
        float wb = w1[(size_t)(64 + k) * HID + tid];
#pragma unroll
        for (int s = 0; s < 8; s++) {
            acc1[s] += emb8[s][k] * wa;
            acc2[s] += emb8[s][k] * wb;
        }
    }
#pragma unroll
    for (int s = 0; s < 8; s++) {
        P1[(size_t)(sbase + s) * HID + tid] = acc1[s];
        P2[(size_t)(sbase + s) * HID + tid] = acc2[s];
    }
}

// ---------- relS = bf16( relu(P1[subj]+P2[obj]+b1) @ w2 + b2 ) via MFMA ----------
__global__ __launch_bounds__(256) void k_rel2(
    const int* __restrict__ subjS, const int* __restrict__ objS,
    const float* __restrict__ P1, const float* __restrict__ P2,
    const float* __restrict__ b1, const unsigned short* __restrict__ w2t,
    const float* __restrict__ b2, unsigned short* __restrict__ relS) {
    __shared__ unsigned short h[128][264];
    int tid = threadIdx.x, lane = tid & 63, w = tid >> 6;
    int rbase = blockIdx.x * 128;
    for (int e = tid; e < 128 * 64; e += 256) {
        int r = e >> 6, jc = (e & 63) * 4;
        int subj = subjS[rbase + r], obj = objS[rbase + r];
        float4 p1 = *(const float4*)&P1[(size_t)subj * HID + jc];
        float4 p2 = *(const float4*)&P2[(size_t)obj * HID + jc];
        float4 bv = *(const float4*)&b1[jc];
        ushort4 hv;
        hv.x = f2bf(fmaxf(p1.x + p2.x + bv.x, 0.f));
        hv.y = f2bf(fmaxf(p1.y + p2.y + bv.y, 0.f));
        hv.z = f2bf(fmaxf(p1.z + p2.z + bv.z, 0.f));
        hv.w = f2bf(fmaxf(p1.w + p2.w + bv.w, 0.f));
        *(ushort4*)&h[r][jc] = hv;
    }
    __syncthreads();
    int lr = lane & 15, lh = lane >> 4;
    f32x4 acc[2][4];
#pragma unroll
    for (int rt = 0; rt < 2; rt++)
#pragma unroll
        for (int ct = 0; ct < 4; ct++) acc[rt][ct] = (f32x4){0.f, 0.f, 0.f, 0.f};
#pragma unroll
    for (int kk = 0; kk < 8; kk++) {
        bf16x8 bfr[4], afr[2];
#pragma unroll
        for (int ct = 0; ct < 4; ct++)
            bfr[ct] = *(const bf16x8*)(w2t + (ct * 16 + lr) * 256 + kk * 32 + lh * 8);
#pragma unroll
        for (int rt = 0; rt < 2; rt++)
            afr[rt] = *(const bf16x8*)&h[w * 32 + rt * 16 + lr][kk * 32 + lh * 8];
#pragma unroll
        for (int rt = 0; rt < 2; rt++)
#pragma unroll
            for (int ct = 0; ct < 4; ct++)
                acc[rt][ct] = __builtin_amdgcn_mfma_f32_16x16x32_bf16(
                    afr[rt], bfr[ct], acc[rt][ct], 0, 0, 0);
    }
    float b2v[4];
#pragma unroll
    for (int ct = 0; ct < 4; ct++) b2v[ct] = b2[ct * 16 + lr];
#pragma unroll
    for (int rt = 0; rt < 2; rt++)
#pragma unroll
        for (int ct = 0; ct < 4; ct++)
#pragma unroll
            for (int rg = 0; rg < 4; rg++) {
                int row = rbase + w * 32 + rt * 16 + lh * 4 + rg;
                relS[(size_t)row * 64 + ct * 16 + lr] =
                    f2bf(acc[rt][ct][rg] + b2v[ct]);
            }
}

// ---------- meta chain: 1024 threads, small reg arrays ----------
__global__ __launch_bounds__(1024) void k_meta(
    const int* __restrict__ x, const float* __restrict__ action_emb,
    const float* __restrict__ pos_emb, const float* __restrict__ q_w,
    const float* __restrict__ q_b, const float* __restrict__ ms_w1,
    const float* __restrict__ ms_b1, const float* __restrict__ ms_w2,
    const float* __restrict__ ms_b2, const float* __restrict__ meta_init,
    unsigned short* __restrict__ metas_bf) {
    __shared__ float sent[L][132];
    __shared__ float qs[A][17];
    __shared__ float qb_lds[L];
    __shared__ float meta_lds[A];
    __shared__ float logits_lds[L];
    __shared__ float attn_lds[L];
    __shared__ float hidden_lds[HID];
    __shared__ float parts[16][65];
    __shared__ float b2_lds[A];
    int tid = threadIdx.x;
    int b = blockIdx.x;
    int lane = tid & 63, wv = tid >> 6;

    for (int i = tid; i < L * 128; i += 1024) {
        int l = i >> 7, d = i & 127;
        float v;
        if (d < 64)
            v = action_emb[x[b * XCOLS + SIZE + l] * 64 + d];
        else
            v = pos_emb[l * 64 + (d - 64)];
        sent[l][d] = v;
    }
    if (tid < A) {
        meta_lds[tid] = meta_init[tid];
        b2_lds[tid] = ms_b2[tid];
    }
    __syncthreads();

    {
        int k = tid >> 4, l = tid & 15;
        float a = 0.f;
        for (int j = 0; j < 128; j++) a += q_w[(size_t)k * 128 + j] * sent[l][j];
        qs[k][l] = a;
    }
    if (tid < L) {
        float a = 0.f;
        for (int j = 0; j < 128; j++) a += q_b[j] * sent[tid][j];
        qb_lds[tid] = a;
    }
    int j_h = tid >> 2, q_h = tid & 3;
    float w1a_r[16];
#pragma unroll
    for (int i = 0; i < 16; i++)
        w1a_r[i] = ms_w1[(size_t)(q_h * 16 + i) * HID + j_h];
    float sentw_r[4];
#pragma unroll
    for (int i = 0; i < 4; i++) sentw_r[i] = 0.f;
    for (int d = 0; d < 128; d++) {
        float w = ms_w1[(size_t)(64 + d) * HID + j_h];
#pragma unroll
        for (int i = 0; i < 4; i++) sentw_r[i] += sent[q_h * 4 + i][d] * w;
    }
    float b1_r = ms_b1[j_h];
    int g_m = tid >> 6, c_m = tid & 63;
    float w2_r[16];
#pragma unroll
    for (int i = 0; i < 16; i++)
        w2_r[i] = ms_w2[(size_t)(g_m * 16 + i) * 64 + c_m];
    __syncthreads();

    for (int t = 0; t < L; t++) {
        float p = meta_lds[lane] * qs[lane][wv];
        p += __shfl_xor(p, 32);
        p += __shfl_xor(p, 16);
        p += __shfl_xor(p, 8);
        p += __shfl_xor(p, 4);
        p += __shfl_xor(p, 2);
        p += __shfl_xor(p, 1);
        if (lane == 0) logits_lds[wv] = p + qb_lds[wv];
        __syncthreads();
        if (tid < L) {
            float mx = logits_lds[0];
#pragma unroll
            for (int l = 1; l < L; l++) mx = fmaxf(mx, logits_lds[l]);
            float sum = 0.f;
#pragma unroll
            for (int l = 0; l < L; l++) sum += __expf(logits_lds[l] - mx);
            attn_lds[tid] = __expf(logits_lds[tid] - mx) / sum;
        }
        __syncthreads();
        float h = 0.f;
#pragma unroll
        for (int i = 0; i < 16; i++) h += meta_lds[q_h * 16 + i] * w1a_r[i];
#pragma unroll
        for (int i = 0; i < 4; i++) h += attn_lds[q_h * 4 + i] * sentw_r[i];
        h += __shfl_xor(h, 1);
        h += __shfl_xor(h, 2);
        if (q_h == 0) hidden_lds[j_h] = fmaxf(h + b1_r, 0.f);
        __syncthreads();
        float pp = 0.f;
#pragma unroll
        for (int i = 0; i < 16; i++) pp += hidden_lds[g_m * 16 + i] * w2_r[i];
        parts[g_m][c_m] = pp;
        __syncthreads();
        if (tid < A) {
            float nm = b2_lds[tid];
#pragma unroll
            for (int g = 0; g < 16; g++) nm += parts[g][tid];
            meta_lds[tid] = nm;
            metas_bf[((size_t)t * B + b) * A + tid] = f2bf(nm);
        }
        __syncthreads();
    }
}

// ---------- fused 16 steps + transpose (cooperative, 256 blocks) ----------
// Each block owns 256 relations; wave w owns rows [w*64, w*64+64) as two
// 32-row windows. vals slab is wave-private -> no intra-step __syncthreads.
__global__ __launch_bounds__(256, 2) void k_steps(
    const int* __restrict__ off, const int* __restrict__ subjS,
    const int* __restrict__ objS, const unsigned short* __restrict__ relS,
    const unsigned short* __restrict__ metas_bf, float* __restrict__ ST,
    float* __restrict__ out) {
    cg::grid_group grid = cg::this_grid();
    __shared__ float vals[4][32][66];
    __shared__ int obj_l[RPC];
    int tid = threadIdx.x, lane = tid & 63, w = tid >> 6;
    int rbase = blockIdx.x * RPC;
    int lr = lane & 15, lh = lane >> 4;

    for (int i = tid; i < RPC; i += 256) obj_l[i] = objS[rbase + i];
    __syncthreads();

    // t-invariant per-window segmentation masks + gather offsets
    unsigned mnew0 = 0, mcont0 = 0, mnew1 = 0, mcont1 = 0;
#pragma unroll
    for (int win = 0; win < 2; win++) {
        unsigned mn = 0, mc = 0;
        int lbase = w * 64 + win * 32;
        int gb = rbase + lbase;
        int obprev = -1;
#pragma unroll
        for (int rr = 0; rr < 32; rr++) {
            int o = obj_l[lbase + rr];
            if (o != obprev) {
                mn |= 1u << rr;
                if (off[o] >= gb && off[o + 1] <= gb + 32) mc |= 1u << rr;
            }
            obprev = o;
        }
        if (win == 0) { mnew0 = mn; mcont0 = mc; }
        else { mnew1 = mn; mcont1 = mc; }
    }
    int goff[64];
#pragma unroll
    for (int rr = 0; rr < 64; rr++)
        goff[rr] = subjS[rbase + w * 64 + rr] * B + lane;

    for (int t = 0; t < L; t++) {
        const unsigned short* mb = metas_bf + (size_t)t * B * A;
        const float* st_in = ST + (size_t)t * SIZE * B;
        float* st_out = ST + (size_t)(t + 1) * SIZE * B;

        bf16x8 bfrag[4][2];
#pragma unroll
        for (int ct = 0; ct < 4; ct++)
#pragma unroll
            for (int kk = 0; kk < 2; kk++)
                bfrag[ct][kk] =
                    *(const bf16x8*)(mb + (ct * 16 + lr) * 64 + kk * 32 + lh * 8);

#pragma unroll
        for (int win = 0; win < 2; win++) {
            int lbase = w * 64 + win * 32;
            int gb = rbase + lbase;
            unsigned mnew = win ? mnew1 : mnew0;
            unsigned mcont = win ? mcont1 : mcont0;

            // issue gathers early; MFMA hides their latency
            float sv[32];
#pragma unroll
            for (int rr = 0; rr < 32; rr++) sv[rr] = st_in[goff[win * 32 + rr]];

            bf16x8 afrag[2][2];
#pragma unroll
            for (int rt = 0; rt < 2; rt++)
#pragma unroll
                for (int kk = 0; kk < 2; kk++)
                    afrag[rt][kk] = *(const bf16x8*)(relS +
                        (size_t)(gb + rt * 16 + lr) * 64 + kk * 32 + lh * 8);

            f32x4 acc[2][4];
#pragma unroll
            for (int rt = 0; rt < 2; rt++)
#pragma unroll
                for (int ct = 0; ct < 4; ct++) {
                    f32x4 c = {0.f, 0.f, 0.f, 0.f};
                    c = __builtin_amdgcn_mfma_f32_16x16x32_bf16(
                        afrag[rt][0], bfrag[ct][0], c, 0, 0, 0);
                    c = __builtin_amdgcn_mfma_f32_16x16x32_bf16(
                        afrag[rt][1], bfrag[ct][1], c, 0, 0, 0);
                    acc[rt][ct] = c;
                }
#pragma unroll
            for (int rt = 0; rt < 2; rt++)
#pragma unroll
                for (int ct = 0; ct < 4; ct++)
#pragma unroll
                    for (int rg = 0; rg < 4; rg++)
                        vals[w][rt * 16 + lh * 4 + rg][ct * 16 + lr] =
                            1.f / (1.f + __expf(-acc[rt][ct][rg]));

            // wave-private vals -> no barrier; flush with precomputed masks
            float acc_s = 0.f;
            int curr = 0;
#pragma unroll
            for (int rr = 0; rr < 32; rr++) {
                if (rr > 0 && ((mnew >> rr) & 1u)) {
                    int o = obj_l[lbase + curr];
                    if ((mcont >> curr) & 1u)
                        st_out[(size_t)o * B + lane] = acc_s;
                    else
                        atomicAdd(&st_out[(size_t)o * B + lane], acc_s);
                    acc_s = 0.f;
                    curr = rr;
                }
                acc_s += vals[w][rr][lane] * sv[rr];
            }
            {
                int o = obj_l[lbase + curr];
                if ((mcont >> curr) & 1u)
                    st_out[(size_t)o * B + lane] = acc_s;
                else
                    atomicAdd(&st_out[(size_t)o * B + lane], acc_s);
            }
        }
        grid.sync();
    }

    // ---- transpose: 512 tasks over 256 blocks ----
    float(*tile)[65] = (float(*)[65])vals;
    for (int task = blockIdx.x; task < 512; task += 256) {
        int t = task >> 5;
        int s0 = (task & 31) * 64;
        const float* src = ST + (size_t)(t + 1) * SIZE * B;
        __syncthreads();
        for (int i = tid; i < 64 * 64; i += 256) {
            int si = i >> 6, b = i & 63;
            tile[si][b] = src[(size_t)(s0 + si) * B + b];
        }
        __syncthreads();
        for (int i = tid; i < 64 * 64; i += 256) {
            int b = i >> 6, si = i & 63;
            out[((size_t)b * L + t) * SIZE + s0 + si] = tile[si][b];
        }
    }
}

// ---------- fallback: single state step (round-5, proven) ----------
__global__ __launch_bounds__(256) void k_step(
    const int* __restrict__ off, const int* __restrict__ subjS,
    const int* __restrict__ objS, const unsigned short* __restrict__ relS,
    const unsigned short* __restrict__ mb, const float* __restrict__ st_in,
    float* __restrict__ st_out) {
    __shared__ float vals[RPB][66];
    int tid = threadIdx.x, lane = tid & 63, w = tid >> 6;
    int rbase = blockIdx.x * RPB;
    int base_w = rbase + w * 32;
    int lr = lane & 15, lh = lane >> 4;

    float sv[32];
    int ob[32];
#pragma unroll
    for (int rr = 0; rr < 32; rr++) {
        sv[rr] = st_in[(size_t)subjS[base_w + rr] * B + lane];
        ob[rr] = objS[base_w + rr];
    }

    bf16x8 bfrag[4][2];
#pragma unroll
    for (int ct = 0; ct < 4; ct++)
#pragma unroll
        for (int kk = 0; kk < 2; kk++)
            bfrag[ct][kk] =
                *(const bf16x8*)(mb + (ct * 16 + lr) * 64 + kk * 32 + lh * 8);
    bf16x8 afrag[2][2];
#pragma unroll
    for (int rt = 0; rt < 2; rt++)
#pragma unroll
        for (int kk = 0; kk < 2; kk++)
            afrag[rt][kk] = *(const bf16x8*)(relS +
                (size_t)(rbase + w * 32 + rt * 16 + lr) * 64 + kk * 32 + lh * 8);

    f32x4 acc[2][4];
#pragma unroll
    for (int rt = 0; rt < 2; rt++)
#pragma unroll
        for (int ct = 0; ct < 4; ct++) {
            f32x4 c = {0.f, 0.f, 0.f, 0.f};
            c = __builtin_amdgcn_mfma_f32_16x16x32_bf16(afrag[rt][0],
                                                        bfrag[ct][0], c, 0, 0, 0);
            c = __builtin_amdgcn_mfma_f32_16x16x32_bf16(afrag[rt][1],
                                                        bfrag[ct][1], c, 0, 0, 0);
            acc[rt][ct] = c;
        }
#pragma unroll
    for (int rt = 0; rt < 2; rt++)
#pragma unroll
        for (int ct = 0; ct < 4; ct++)
#pragma unroll
            for (int rg = 0; rg < 4; rg++) {
                int r_loc = w * 32 + rt * 16 + lh * 4 + rg;
                int c = ct * 16 + lr;
                vals[r_loc][c] = 1.f / (1.f + __expf(-acc[rt][ct][rg]));
            }
    __syncthreads();

    float acc_s = 0.f;
    int cur = ob[0];
#pragma unroll
    for (int rr = 0; rr < 32; rr++) {
        float v = vals[w * 32 + rr][lane] * sv[rr];
        if (ob[rr] != cur) {
            int s = off[cur], e = off[cur + 1];
            if (s >= base_w && e <= base_w + 32)
                st_out[(size_t)cur * B + lane] = acc_s;
            else
                atomicAdd(&st_out[(size_t)cur * B + lane], acc_s);
            acc_s = 0.f;
            cur = ob[rr];
        }
        acc_s += v;
    }
    {
        int s = off[cur], e = off[cur + 1];
        if (s >= base_w && e <= base_w + 32)
            st_out[(size_t)cur * B + lane] = acc_s;
        else
            atomicAdd(&st_out[(size_t)cur * B + lane], acc_s);
    }
}

// ---------- fallback final transpose ----------
__global__ __launch_bounds__(256) void k_out(const float* __restrict__ ST,
                                             float* __restrict__ out) {
    __shared__ float tile[64][65];
    int t = blockIdx.x >> 5;
    int s0 = (blockIdx.x & 31) * 64;
    const float* src = ST + (size_t)(t + 1) * SIZE * B;
    int tid = threadIdx.x;
    for (int i = tid; i < 64 * 64; i += 256) {
        int si = i >> 6, b = i & 63;
        tile[si][b] = src[(size_t)(s0 + si) * B + b];
    }
    __syncthreads();
    for (int i = tid; i < 64 * 64; i += 256) {
        int b = i >> 6, si = i & 63;
        out[((size_t)b * L + t) * SIZE + s0 + si] = tile[si][b];
    }
}

extern "C" void kernel_launch(void* const* d_in, const int* in_sizes, int n_in,
                              void* d_out, int out_size, void* d_ws,
                              size_t ws_size, hipStream_t stream) {
    const int* x = (const int*)d_in[0];
    const int* rel_subj = (const int*)d_in[1];
    const int* rel_obj = (const int*)d_in[2];
    const float* action_emb = (const float*)d_in[3];
    const float* pos_emb = (const float*)d_in[4];
    const float* state_emb = (const float*)d_in[5];
    const float* s2r_w1 = (const float*)d_in[6];
    const float* s2r_b1 = (const float*)d_in[7];
    const float* s2r_w2 = (const float*)d_in[8];
    const float* s2r_b2 = (const float*)d_in[9];
    const float* q_w = (const float*)d_in[10];
    const float* q_b = (const float*)d_in[11];
    const float* ms_w1 = (const float*)d_in[12];
    const float* ms_b1 = (const float*)d_in[13];
    const float* ms_w2 = (const float*)d_in[14];
    const float* ms_b2 = (const float*)d_in[15];
    const float* meta_init = (const float*)d_in[16];

    float* ws = (float*)d_ws;
    float* ST = ws;
    unsigned short* relS = (unsigned short*)(ws + ST_ELEMS);
    unsigned short* metas_bf = relS + (size_t)R_N * 64;
    float* P1 = (float*)(metas_bf + (size_t)L * B * A);
    float* P2 = P1 + SIZE * HID;
    int* ibase = (int*)(P2 + SIZE * HID);
    int* hist = ibase;
    int* off = ibase + 2048;
    int* cursor = off + 2049;
    int* subjS = cursor + 2048;
    int* objS = subjS + R_N;
    unsigned short* w2t = (unsigned short*)d_out;  // overwritten by transpose
    float* out = (float*)d_out;

    k_init<<<256, 256, 0, stream>>>(x, ST, hist, cursor);
    k_hist<<<64, 256, 0, stream>>>(rel_obj, hist);
    k_scan<<<2, 256, 0, stream>>>(hist, off, s2r_w2, w2t);
    k_scatter<<<64, 256, 0, stream>>>(rel_subj, rel_obj, off, cursor, subjS, objS);
    k_p12<<<SIZE / 8, 256, 0, stream>>>(state_emb, s2r_w1, P1, P2);
    k_rel2<<<R_N / RPB, 256, 0, stream>>>(subjS, objS, P1, P2, s2r_b1, w2t,
                                          s2r_b2, relS);
    k_meta<<<B, 1024, 0, stream>>>(x, action_emb, pos_emb, q_w, q_b, ms_w1,
                                   ms_b1, ms_w2, ms_b2, meta_init, metas_bf);

    void* args[] = {(void*)&off,   (void*)&subjS,    (void*)&objS,
                    (void*)&relS,  (void*)&metas_bf, (void*)&ST,
                    (void*)&out};
    hipError_t ce = hipLaunchCooperativeKernel((const void*)k_steps,
                                               dim3(R_N / RPC), dim3(256), args,
                                               0, stream);
    if (ce != hipSuccess) {
        // fallback: proven 16-launch path
        for (int t = 0; t < L; t++) {
            k_step<<<R_N / RPB, 256, 0, stream>>>(
                off, subjS, objS, relS, metas_bf + (size_t)t * B * A,
                ST + (size_t)t * SIZE * B, ST + (size_t)(t + 1) * SIZE * B);
        }
        k_out<<<512, 256, 0, stream>>>(ST, out);
    }
}

// Round 8
// 730.494 us; speedup vs baseline: 1.0976x; 1.0976x over previous
//
#include <hip/hip_runtime.h>
#include <hip/hip_cooperative_groups.h>

namespace cg = cooperative_groups;

#define B 64
#define SIZE 2048
#define L 16
#define A 64
#define HID 256
#define R_N 65536
#define XCOLS (SIZE + L)
#define ST_ELEMS ((L + 1) * SIZE * B)
#define RPB 128
#define RPC 256

typedef short bf16x8 __attribute__((ext_vector_type(8)));
typedef float f32x4 __attribute__((ext_vector_type(4)));

__device__ __forceinline__ unsigned short f2bf(float f) {
    unsigned int u = __float_as_uint(f);
    unsigned int r = (u + 0x7fffu + ((u >> 16) & 1u)) >> 16;
    return (unsigned short)r;
}

// ---------- init: zero ST[1..16], ST[0] = x^T, zero hist/cursor ----------
__global__ __launch_bounds__(256) void k_init(const int* __restrict__ x,
                                              float* __restrict__ ST,
                                              int* __restrict__ hist,
                                              int* __restrict__ cursor) {
    int tid = threadIdx.x;
    float4* z = (float4*)(ST + (size_t)SIZE * B);
    int total4 = L * SIZE * B / 4;
    float4 zv = {0.f, 0.f, 0.f, 0.f};
    for (int i = blockIdx.x * 256 + tid; i < total4; i += gridDim.x * 256)
        z[i] = zv;
    if (blockIdx.x == 32) {
        for (int i = tid; i < 2048; i += 256) {
            hist[i] = 0;
            cursor[i] = 0;
        }
    }
    if (blockIdx.x < 32) {
        __shared__ float tile[64][65];
        int s0 = blockIdx.x * 64;
        for (int i = tid; i < 4096; i += 256) {
            int b = i >> 6, sc = i & 63;
            tile[b][sc] = (float)x[b * XCOLS + s0 + sc];
        }
        __syncthreads();
        for (int i = tid; i < 4096; i += 256) {
            int si = i >> 6, b = i & 63;
            ST[(size_t)(s0 + si) * B + b] = tile[b][si];
        }
    }
}

// ---------- histogram of rel_obj ----------
__global__ __launch_bounds__(256) void k_hist(const int* __restrict__ rel_obj,
                                              int* __restrict__ hist) {
    for (int i = blockIdx.x * 256 + threadIdx.x; i < R_N; i += 64 * 256)
        atomicAdd(&hist[rel_obj[i]], 1);
}

// ---------- block 0: exclusive scan; block 1: w2t = bf16(w2^T) ----------
__global__ __launch_bounds__(256) void k_scan(const int* __restrict__ hist,
                                              int* __restrict__ off,
                                              const float* __restrict__ w2,
                                              unsigned short* __restrict__ w2t) {
    int tid = threadIdx.x;
    if (blockIdx.x == 1) {
        for (int i = tid; i < 64 * 256; i += 256) {
            int c = i >> 8, k = i & 255;
            w2t[i] = f2bf(w2[(size_t)k * 64 + c]);
        }
        return;
    }
    __shared__ int tsum[256];
    int v[8], pre[8];
    int s = 0;
#pragma unroll
    for (int i = 0; i < 8; i++) {
        v[i] = hist[tid * 8 + i];
        pre[i] = s;
        s += v[i];
    }
    tsum[tid] = s;
    __syncthreads();
    for (int ofs = 1; ofs < 256; ofs <<= 1) {
        int t = 0;
        if (tid >= ofs) t = tsum[tid - ofs];
        __syncthreads();
        tsum[tid] += t;
        __syncthreads();
    }
    int ebase = tsum[tid] - s;
#pragma unroll
    for (int i = 0; i < 8; i++) off[tid * 8 + i] = ebase + pre[i];
    if (tid == 255) off[2048] = tsum[255];
}

// ---------- scatter sorted positions ----------
__global__ __launch_bounds__(256) void k_scatter(const int* __restrict__ rel_subj,
                                                 const int* __restrict__ rel_obj,
                                                 const int* __restrict__ off,
                                                 int* __restrict__ cursor,
                                                 int* __restrict__ subjS,
                                                 int* __restrict__ objS) {
    for (int r = blockIdx.x * 256 + threadIdx.x; r < R_N; r += 64 * 256) {
        int obj = rel_obj[r];
        int pos = off[obj] + atomicAdd(&cursor[obj], 1);
        subjS[pos] = rel_subj[r];
        objS[pos] = obj;
    }
}

// ---------- P1 = emb @ W1a, P2 = emb @ W1b ----------
__global__ __launch_bounds__(256) void k_p12(const float* __restrict__ state_emb,
                                             const float* __restrict__ w1,
                                             float* __restrict__ P1,
                                             float* __restrict__ P2) {
    __shared__ float emb8[8][64];
    int tid = threadIdx.x;
    int sbase = blockIdx.x * 8;
    for (int i = tid; i < 512; i += 256)
        emb8[i >> 6][i & 63] = state_emb[(size_t)(sbase + (i >> 6)) * 64 + (i & 63)];
    __syncthreads();
    float acc1[8], acc2[8];
#pragma unroll
    for (int s = 0; s < 8; s++) { acc1[s] = 0.f; acc2[s] = 0.f; }
    for (int k = 0; k < 64; k++) {
        float wa = w1[(size_t)k * HID + tid];
        float wb = w1[(size_t)(64 + k) * HID + tid];
#pragma unroll
        for (int s = 0; s < 8; s++) {
            acc1[s] += emb8[s][k] * wa;
            acc2[s] += emb8[s][k] * wb;
        }
    }
#pragma unroll
    for (int s = 0; s < 8; s++) {
        P1[(size_t)(sbase + s) * HID + tid] = acc1[s];
        P2[(size_t)(sbase + s) * HID + tid] = acc2[s];
    }
}

// ---------- relS = bf16( relu(P1[subj]+P2[obj]+b1) @ w2 + b2 ) via MFMA ----------
__global__ __launch_bounds__(256) void k_rel2(
    const int* __restrict__ subjS, const int* __restrict__ objS,
    const float* __restrict__ P1, const float* __restrict__ P2,
    const float* __restrict__ b1, const unsigned short* __restrict__ w2t,
    const float* __restrict__ b2, unsigned short* __restrict__ relS) {
    __shared__ unsigned short h[128][264];
    int tid = threadIdx.x, lane = tid & 63, w = tid >> 6;
    int rbase = blockIdx.x * 128;
    for (int e = tid; e < 128 * 64; e += 256) {
        int r = e >> 6, jc = (e & 63) * 4;
        int subj = subjS[rbase + r], obj = objS[rbase + r];
        float4 p1 = *(const float4*)&P1[(size_t)subj * HID + jc];
        float4 p2 = *(const float4*)&P2[(size_t)obj * HID + jc];
        float4 bv = *(const float4*)&b1[jc];
        ushort4 hv;
        hv.x = f2bf(fmaxf(p1.x + p2.x + bv.x, 0.f));
        hv.y = f2bf(fmaxf(p1.y + p2.y + bv.y, 0.f));
        hv.z = f2bf(fmaxf(p1.z + p2.z + bv.z, 0.f));
        hv.w = f2bf(fmaxf(p1.w + p2.w + bv.w, 0.f));
        *(ushort4*)&h[r][jc] = hv;
    }
    __syncthreads();
    int lr = lane & 15, lh = lane >> 4;
    f32x4 acc[2][4];
#pragma unroll
    for (int rt = 0; rt < 2; rt++)
#pragma unroll
        for (int ct = 0; ct < 4; ct++) acc[rt][ct] = (f32x4){0.f, 0.f, 0.f, 0.f};
#pragma unroll
    for (int kk = 0; kk < 8; kk++) {
        bf16x8 bfr[4], afr[2];
#pragma unroll
        for (int ct = 0; ct < 4; ct++)
            bfr[ct] = *(const bf16x8*)(w2t + (ct * 16 + lr) * 256 + kk * 32 + lh * 8);
#pragma unroll
        for (int rt = 0; rt < 2; rt++)
            afr[rt] = *(const bf16x8*)&h[w * 32 + rt * 16 + lr][kk * 32 + lh * 8];
#pragma unroll
        for (int rt = 0; rt < 2; rt++)
#pragma unroll
            for (int ct = 0; ct < 4; ct++)
                acc[rt][ct] = __builtin_amdgcn_mfma_f32_16x16x32_bf16(
                    afr[rt], bfr[ct], acc[rt][ct], 0, 0, 0);
    }
    float b2v[4];
#pragma unroll
    for (int ct = 0; ct < 4; ct++) b2v[ct] = b2[ct * 16 + lr];
#pragma unroll
    for (int rt = 0; rt < 2; rt++)
#pragma unroll
        for (int ct = 0; ct < 4; ct++)
#pragma unroll
            for (int rg = 0; rg < 4; rg++) {
                int row = rbase + w * 32 + rt * 16 + lh * 4 + rg;
                relS[(size_t)row * 64 + ct * 16 + lr] =
                    f2bf(acc[rt][ct][rg] + b2v[ct]);
            }
}

// ---------- meta chain: 1024 threads, small reg arrays ----------
__global__ __launch_bounds__(1024) void k_meta(
    const int* __restrict__ x, const float* __restrict__ action_emb,
    const float* __restrict__ pos_emb, const float* __restrict__ q_w,
    const float* __restrict__ q_b, const float* __restrict__ ms_w1,
    const float* __restrict__ ms_b1, const float* __restrict__ ms_w2,
    const float* __restrict__ ms_b2, const float* __restrict__ meta_init,
    unsigned short* __restrict__ metas_bf) {
    __shared__ float sent[L][132];
    __shared__ float qs[A][17];
    __shared__ float qb_lds[L];
    __shared__ float meta_lds[A];
    __shared__ float logits_lds[L];
    __shared__ float attn_lds[L];
    __shared__ float hidden_lds[HID];
    __shared__ float parts[16][65];
    __shared__ float b2_lds[A];
    int tid = threadIdx.x;
    int b = blockIdx.x;
    int lane = tid & 63, wv = tid >> 6;

    for (int i = tid; i < L * 128; i += 1024) {
        int l = i >> 7, d = i & 127;
        float v;
        if (d < 64)
            v = action_emb[x[b * XCOLS + SIZE + l] * 64 + d];
        else
            v = pos_emb[l * 64 + (d - 64)];
        sent[l][d] = v;
    }
    if (tid < A) {
        meta_lds[tid] = meta_init[tid];
        b2_lds[tid] = ms_b2[tid];
    }
    __syncthreads();

    {
        int k = tid >> 4, l = tid & 15;
        float a = 0.f;
        for (int j = 0; j < 128; j++) a += q_w[(size_t)k * 128 + j] * sent[l][j];
        qs[k][l] = a;
    }
    if (tid < L) {
        float a = 0.f;
        for (int j = 0; j < 128; j++) a += q_b[j] * sent[tid][j];
        qb_lds[tid] = a;
    }
    int j_h = tid >> 2, q_h = tid & 3;
    float w1a_r[16];
#pragma unroll
    for (int i = 0; i < 16; i++)
        w1a_r[i] = ms_w1[(size_t)(q_h * 16 + i) * HID + j_h];
    float sentw_r[4];
#pragma unroll
    for (int i = 0; i < 4; i++) sentw_r[i] = 0.f;
    for (int d = 0; d < 128; d++) {
        float w = ms_w1[(size_t)(64 + d) * HID + j_h];
#pragma unroll
        for (int i = 0; i < 4; i++) sentw_r[i] += sent[q_h * 4 + i][d] * w;
    }
    float b1_r = ms_b1[j_h];
    int g_m = tid >> 6, c_m = tid & 63;
    float w2_r[16];
#pragma unroll
    for (int i = 0; i < 16; i++)
        w2_r[i] = ms_w2[(size_t)(g_m * 16 + i) * 64 + c_m];
    __syncthreads();

    for (int t = 0; t < L; t++) {
        float p = meta_lds[lane] * qs[lane][wv];
        p += __shfl_xor(p, 32);
        p += __shfl_xor(p, 16);
        p += __shfl_xor(p, 8);
        p += __shfl_xor(p, 4);
        p += __shfl_xor(p, 2);
        p += __shfl_xor(p, 1);
        if (lane == 0) logits_lds[wv] = p + qb_lds[wv];
        __syncthreads();
        if (tid < L) {
            float mx = logits_lds[0];
#pragma unroll
            for (int l = 1; l < L; l++) mx = fmaxf(mx, logits_lds[l]);
            float sum = 0.f;
#pragma unroll
            for (int l = 0; l < L; l++) sum += __expf(logits_lds[l] - mx);
            attn_lds[tid] = __expf(logits_lds[tid] - mx) / sum;
        }
        __syncthreads();
        float h = 0.f;
#pragma unroll
        for (int i = 0; i < 16; i++) h += meta_lds[q_h * 16 + i] * w1a_r[i];
#pragma unroll
        for (int i = 0; i < 4; i++) h += attn_lds[q_h * 4 + i] * sentw_r[i];
        h += __shfl_xor(h, 1);
        h += __shfl_xor(h, 2);
        if (q_h == 0) hidden_lds[j_h] = fmaxf(h + b1_r, 0.f);
        __syncthreads();
        float pp = 0.f;
#pragma unroll
        for (int i = 0; i < 16; i++) pp += hidden_lds[g_m * 16 + i] * w2_r[i];
        parts[g_m][c_m] = pp;
        __syncthreads();
        if (tid < A) {
            float nm = b2_lds[tid];
#pragma unroll
            for (int g = 0; g < 16; g++) nm += parts[g][tid];
            meta_lds[tid] = nm;
            metas_bf[((size_t)t * B + b) * A + tid] = f2bf(nm);
        }
        __syncthreads();
    }
}

// ---------- fused 16 steps + transpose (cooperative, 256 blocks x 512) ----------
// 8 waves/block, wave owns 32 rows (= proven round-5 flush window).
// afrag persistent; no goff array (recomputed from subj_l) -> no spill.
// vals LDS is f32 but half-window [8][16][66]: flush in two 16-row phases.
__global__ __launch_bounds__(512) void k_steps(
    const int* __restrict__ off, const int* __restrict__ subjS,
    const int* __restrict__ objS, const unsigned short* __restrict__ relS,
    const unsigned short* __restrict__ metas_bf, float* __restrict__ ST,
    float* __restrict__ out) {
    cg::grid_group grid = cg::this_grid();
    __shared__ float vals[8][16][66];  // 33 KB; reused as tile later
    __shared__ int obj_l[RPC], subj_l[RPC];
    int tid = threadIdx.x, lane = tid & 63, w = tid >> 6;  // w in 0..7
    int rbase = blockIdx.x * RPC;
    int lbase = w * 32;
    int gb = rbase + lbase;
    int lr = lane & 15, lh = lane >> 4;

    for (int i = tid; i < RPC; i += 512) {
        obj_l[i] = objS[rbase + i];
        subj_l[i] = subjS[rbase + i];
    }
    __syncthreads();

    // t-invariant segmentation masks (wave-uniform)
    unsigned mnew = 0, mcont = 0;
    {
        int obprev = -1;
#pragma unroll
        for (int rr = 0; rr < 32; rr++) {
            int o = obj_l[lbase + rr];
            if (o != obprev) {
                mnew |= 1u << rr;
                if (off[o] >= gb && off[o + 1] <= gb + 32) mcont |= 1u << rr;
            }
            obprev = o;
        }
    }

    // A fragments: persistent across all 16 steps (t-invariant)
    bf16x8 afrag[2][2];
#pragma unroll
    for (int rt = 0; rt < 2; rt++)
#pragma unroll
        for (int kk = 0; kk < 2; kk++)
            afrag[rt][kk] = *(const bf16x8*)(relS +
                (size_t)(gb + rt * 16 + lr) * 64 + kk * 32 + lh * 8);

    for (int t = 0; t < L; t++) {
        const unsigned short* mb = metas_bf + (size_t)t * B * A;
        const float* st_in = ST + (size_t)t * SIZE * B;
        float* st_out = ST + (size_t)(t + 1) * SIZE * B;

        // issue gathers first; MFMA hides their latency
        float sv[32];
#pragma unroll
        for (int rr = 0; rr < 32; rr++)
            sv[rr] = st_in[(size_t)subj_l[lbase + rr] * B + lane];

        bf16x8 bfrag[4][2];
#pragma unroll
        for (int ct = 0; ct < 4; ct++)
#pragma unroll
            for (int kk = 0; kk < 2; kk++)
                bfrag[ct][kk] =
                    *(const bf16x8*)(mb + (ct * 16 + lr) * 64 + kk * 32 + lh * 8);

        f32x4 acc[2][4];
#pragma unroll
        for (int rt = 0; rt < 2; rt++)
#pragma unroll
            for (int ct = 0; ct < 4; ct++) {
                f32x4 c = {0.f, 0.f, 0.f, 0.f};
                c = __builtin_amdgcn_mfma_f32_16x16x32_bf16(
                    afrag[rt][0], bfrag[ct][0], c, 0, 0, 0);
                c = __builtin_amdgcn_mfma_f32_16x16x32_bf16(
                    afrag[rt][1], bfrag[ct][1], c, 0, 0, 0);
                acc[rt][ct] = c;
            }

        // flush in two 16-row phases (wave-private LDS slab, no barriers)
        float acc_s = 0.f;
        int curr = 0;
#pragma unroll
        for (int rt = 0; rt < 2; rt++) {
#pragma unroll
            for (int ct = 0; ct < 4; ct++)
#pragma unroll
                for (int rg = 0; rg < 4; rg++)
                    vals[w][lh * 4 + rg][ct * 16 + lr] =
                        1.f / (1.f + __expf(-acc[rt][ct][rg]));
#pragma unroll
            for (int i = 0; i < 16; i++) {
                int rr = rt * 16 + i;
                if (rr > 0 && ((mnew >> rr) & 1u)) {
                    int o = obj_l[lbase + curr];
                    if ((mcont >> curr) & 1u)
                        st_out[(size_t)o * B + lane] = acc_s;
                    else
                        atomicAdd(&st_out[(size_t)o * B + lane], acc_s);
                    acc_s = 0.f;
                    curr = rr;
                }
                acc_s += vals[w][i][lane] * sv[rr];
            }
        }
        {
            int o = obj_l[lbase + curr];
            if ((mcont >> curr) & 1u)
                st_out[(size_t)o * B + lane] = acc_s;
            else
                atomicAdd(&st_out[(size_t)o * B + lane], acc_s);
        }
        grid.sync();
    }

    // ---- transpose: 512 tasks over 256 blocks, 512 threads each ----
    float(*tile)[65] = (float(*)[65])vals;
    for (int task = blockIdx.x; task < 512; task += 256) {
        int t = task >> 5;
        int s0 = (task & 31) * 64;
        const float* src = ST + (size_t)(t + 1) * SIZE * B;
        __syncthreads();
        for (int i = tid; i < 64 * 64; i += 512) {
            int si = i >> 6, b = i & 63;
            tile[si][b] = src[(size_t)(s0 + si) * B + b];
        }
        __syncthreads();
        for (int i = tid; i < 64 * 64; i += 512) {
            int b = i >> 6, si = i & 63;
            out[((size_t)b * L + t) * SIZE + s0 + si] = tile[si][b];
        }
    }
}

// ---------- fallback: single state step (round-5, proven) ----------
__global__ __launch_bounds__(256) void k_step(
    const int* __restrict__ off, const int* __restrict__ subjS,
    const int* __restrict__ objS, const unsigned short* __restrict__ relS,
    const unsigned short* __restrict__ mb, const float* __restrict__ st_in,
    float* __restrict__ st_out) {
    __shared__ float vals[RPB][66];
    int tid = threadIdx.x, lane = tid & 63, w = tid >> 6;
    int rbase = blockIdx.x * RPB;
    int base_w = rbase + w * 32;
    int lr = lane & 15, lh = lane >> 4;

    float sv[32];
    int ob[32];
#pragma unroll
    for (int rr = 0; rr < 32; rr++) {
        sv[rr] = st_in[(size_t)subjS[base_w + rr] * B + lane];
        ob[rr] = objS[base_w + rr];
    }

    bf16x8 bfrag[4][2];
#pragma unroll
    for (int ct = 0; ct < 4; ct++)
#pragma unroll
        for (int kk = 0; kk < 2; kk++)
            bfrag[ct][kk] =
                *(const bf16x8*)(mb + (ct * 16 + lr) * 64 + kk * 32 + lh * 8);
    bf16x8 afrag[2][2];
#pragma unroll
    for (int rt = 0; rt < 2; rt++)
#pragma unroll
        for (int kk = 0; kk < 2; kk++)
            afrag[rt][kk] = *(const bf16x8*)(relS +
                (size_t)(rbase + w * 32 + rt * 16 + lr) * 64 + kk * 32 + lh * 8);

    f32x4 acc[2][4];
#pragma unroll
    for (int rt = 0; rt < 2; rt++)
#pragma unroll
        for (int ct = 0; ct < 4; ct++) {
            f32x4 c = {0.f, 0.f, 0.f, 0.f};
            c = __builtin_amdgcn_mfma_f32_16x16x32_bf16(afrag[rt][0],
                                                        bfrag[ct][0], c, 0, 0, 0);
            c = __builtin_amdgcn_mfma_f32_16x16x32_bf16(afrag[rt][1],
                                                        bfrag[ct][1], c, 0, 0, 0);
            acc[rt][ct] = c;
        }
#pragma unroll
    for (int rt = 0; rt < 2; rt++)
#pragma unroll
        for (int ct = 0; ct < 4; ct++)
#pragma unroll
            for (int rg = 0; rg < 4; rg++) {
                int r_loc = w * 32 + rt * 16 + lh * 4 + rg;
                int c = ct * 16 + lr;
                vals[r_loc][c] = 1.f / (1.f + __expf(-acc[rt][ct][rg]));
            }
    __syncthreads();

    float acc_s = 0.f;
    int cur = ob[0];
#pragma unroll
    for (int rr = 0; rr < 32; rr++) {
        float v = vals[w * 32 + rr][lane] * sv[rr];
        if (ob[rr] != cur) {
            int s = off[cur], e = off[cur + 1];
            if (s >= base_w && e <= base_w + 32)
                st_out[(size_t)cur * B + lane] = acc_s;
            else
                atomicAdd(&st_out[(size_t)cur * B + lane], acc_s);
            acc_s = 0.f;
            cur = ob[rr];
        }
        acc_s += v;
    }
    {
        int s = off[cur], e = off[cur + 1];
        if (s >= base_w && e <= base_w + 32)
            st_out[(size_t)cur * B + lane] = acc_s;
        else
            atomicAdd(&st_out[(size_t)cur * B + lane], acc_s);
    }
}

// ---------- fallback final transpose ----------
__global__ __launch_bounds__(256) void k_out(const float* __restrict__ ST,
                                             float* __restrict__ out) {
    __shared__ float tile[64][65];
    int t = blockIdx.x >> 5;
    int s0 = (blockIdx.x & 31) * 64;
    const float* src = ST + (size_t)(t + 1) * SIZE * B;
    int tid = threadIdx.x;
    for (int i = tid; i < 64 * 64; i += 256) {
        int si = i >> 6, b = i & 63;
        tile[si][b] = src[(size_t)(s0 + si) * B + b];
    }
    __syncthreads();
    for (int i = tid; i < 64 * 64; i += 256) {
        int b = i >> 6, si = i & 63;
        out[((size_t)b * L + t) * SIZE + s0 + si] = tile[si][b];
    }
}

extern "C" void kernel_launch(void* const* d_in, const int* in_sizes, int n_in,
                              void* d_out, int out_size, void* d_ws,
                              size_t ws_size, hipStream_t stream) {
    const int* x = (const int*)d_in[0];
    const int* rel_subj = (const int*)d_in[1];
    const int* rel_obj = (const int*)d_in[2];
    const float* action_emb = (const float*)d_in[3];
    const float* pos_emb = (const float*)d_in[4];
    const float* state_emb = (const float*)d_in[5];
    const float* s2r_w1 = (const float*)d_in[6];
    const float* s2r_b1 = (const float*)d_in[7];
    const float* s2r_w2 = (const float*)d_in[8];
    const float* s2r_b2 = (const float*)d_in[9];
    const float* q_w = (const float*)d_in[10];
    const float* q_b = (const float*)d_in[11];
    const float* ms_w1 = (const float*)d_in[12];
    const float* ms_b1 = (const float*)d_in[13];
    const float* ms_w2 = (const float*)d_in[14];
    const float* ms_b2 = (const float*)d_in[15];
    const float* meta_init = (const float*)d_in[16];

    float* ws = (float*)d_ws;
    float* ST = ws;
    unsigned short* relS = (unsigned short*)(ws + ST_ELEMS);
    unsigned short* metas_bf = relS + (size_t)R_N * 64;
    float* P1 = (float*)(metas_bf + (size_t)L * B * A);
    float* P2 = P1 + SIZE * HID;
    int* ibase = (int*)(P2 + SIZE * HID);
    int* hist = ibase;
    int* off = ibase + 2048;
    int* cursor = off + 2049;
    int* subjS = cursor + 2048;
    int* objS = subjS + R_N;
    unsigned short* w2t = (unsigned short*)d_out;  // overwritten by transpose
    float* out = (float*)d_out;

    k_init<<<256, 256, 0, stream>>>(x, ST, hist, cursor);
    k_hist<<<64, 256, 0, stream>>>(rel_obj, hist);
    k_scan<<<2, 256, 0, stream>>>(hist, off, s2r_w2, w2t);
    k_scatter<<<64, 256, 0, stream>>>(rel_subj, rel_obj, off, cursor, subjS, objS);
    k_p12<<<SIZE / 8, 256, 0, stream>>>(state_emb, s2r_w1, P1, P2);
    k_rel2<<<R_N / RPB, 256, 0, stream>>>(subjS, objS, P1, P2, s2r_b1, w2t,
                                          s2r_b2, relS);
    k_meta<<<B, 1024, 0, stream>>>(x, action_emb, pos_emb, q_w, q_b, ms_w1,
                                   ms_b1, ms_w2, ms_b2, meta_init, metas_bf);

    void* args[] = {(void*)&off,   (void*)&subjS,    (void*)&objS,
                    (void*)&relS,  (void*)&metas_bf, (void*)&ST,
                    (void*)&out};
    hipError_t ce = hipLaunchCooperativeKernel((const void*)k_steps,
                                               dim3(R_N / RPC), dim3(512), args,
                                               0, stream);
    if (ce != hipSuccess) {
        for (int t = 0; t < L; t++) {
            k_step<<<R_N / RPB, 256, 0, stream>>>(
                off, subjS, objS, relS, metas_bf + (size_t)t * B * A,
                ST + (size_t)t * SIZE * B, ST + (size_t)(t + 1) * SIZE * B);
        }
        k_out<<<512, 256, 0, stream>>>(ST, out);
    }
}

// Round 9
// 358.343 us; speedup vs baseline: 2.2375x; 2.0385x over previous
//
#include <hip/hip_runtime.h>

#define B 64
#define SIZE 2048
#define L 16
#define A 64
#define HID 256
#define R_N 65536
#define XCOLS (SIZE + L)
#define ST_ELEMS ((L + 1) * SIZE * B)
#define RPB 128

typedef short bf16x8 __attribute__((ext_vector_type(8)));
typedef float f32x4 __attribute__((ext_vector_type(4)));

__device__ __forceinline__ unsigned short f2bf(float f) {
    unsigned int u = __float_as_uint(f);
    unsigned int r = (u + 0x7fffu + ((u >> 16) & 1u)) >> 16;
    return (unsigned short)r;
}

// ---------- init: zero ST[1..16], ST[0] = x^T, zero hist/cursor ----------
__global__ __launch_bounds__(256) void k_init(const int* __restrict__ x,
                                              float* __restrict__ ST,
                                              int* __restrict__ hist,
                                              int* __restrict__ cursor) {
    int tid = threadIdx.x;
    float4* z = (float4*)(ST + (size_t)SIZE * B);
    int total4 = L * SIZE * B / 4;
    float4 zv = {0.f, 0.f, 0.f, 0.f};
    for (int i = blockIdx.x * 256 + tid; i < total4; i += gridDim.x * 256)
        z[i] = zv;
    if (blockIdx.x == 32) {
        for (int i = tid; i < 2048; i += 256) {
            hist[i] = 0;
            cursor[i] = 0;
        }
    }
    if (blockIdx.x < 32) {
        __shared__ float tile[64][65];
        int s0 = blockIdx.x * 64;
        for (int i = tid; i < 4096; i += 256) {
            int b = i >> 6, sc = i & 63;
            tile[b][sc] = (float)x[b * XCOLS + s0 + sc];
        }
        __syncthreads();
        for (int i = tid; i < 4096; i += 256) {
            int si = i >> 6, b = i & 63;
            ST[(size_t)(s0 + si) * B + b] = tile[b][si];
        }
    }
}

// ---------- histogram of rel_obj ----------
__global__ __launch_bounds__(256) void k_hist(const int* __restrict__ rel_obj,
                                              int* __restrict__ hist) {
    for (int i = blockIdx.x * 256 + threadIdx.x; i < R_N; i += 64 * 256)
        atomicAdd(&hist[rel_obj[i]], 1);
}

// ---------- block 0: exclusive scan; block 1: w2t = bf16(w2^T) ----------
__global__ __launch_bounds__(256) void k_scan(const int* __restrict__ hist,
                                              int* __restrict__ off,
                                              const float* __restrict__ w2,
                                              unsigned short* __restrict__ w2t) {
    int tid = threadIdx.x;
    if (blockIdx.x == 1) {
        for (int i = tid; i < 64 * 256; i += 256) {
            int c = i >> 8, k = i & 255;
            w2t[i] = f2bf(w2[(size_t)k * 64 + c]);
        }
        return;
    }
    __shared__ int tsum[256];
    int v[8], pre[8];
    int s = 0;
#pragma unroll
    for (int i = 0; i < 8; i++) {
        v[i] = hist[tid * 8 + i];
        pre[i] = s;
        s += v[i];
    }
    tsum[tid] = s;
    __syncthreads();
    for (int ofs = 1; ofs < 256; ofs <<= 1) {
        int t = 0;
        if (tid >= ofs) t = tsum[tid - ofs];
        __syncthreads();
        tsum[tid] += t;
        __syncthreads();
    }
    int ebase = tsum[tid] - s;
#pragma unroll
    for (int i = 0; i < 8; i++) off[tid * 8 + i] = ebase + pre[i];
    if (tid == 255) off[2048] = tsum[255];
}

// ---------- scatter sorted positions ----------
__global__ __launch_bounds__(256) void k_scatter(const int* __restrict__ rel_subj,
                                                 const int* __restrict__ rel_obj,
                                                 const int* __restrict__ off,
                                                 int* __restrict__ cursor,
                                                 int* __restrict__ subjS,
                                                 int* __restrict__ objS) {
    for (int r = blockIdx.x * 256 + threadIdx.x; r < R_N; r += 64 * 256) {
        int obj = rel_obj[r];
        int pos = off[obj] + atomicAdd(&cursor[obj], 1);
        subjS[pos] = rel_subj[r];
        objS[pos] = obj;
    }
}

// ---------- P1 = emb @ W1a, P2 = emb @ W1b ----------
__global__ __launch_bounds__(256) void k_p12(const float* __restrict__ state_emb,
                                             const float* __restrict__ w1,
                                             float* __restrict__ P1,
                                             float* __restrict__ P2) {
    __shared__ float emb8[8][64];
    int tid = threadIdx.x;
    int sbase = blockIdx.x * 8;
    for (int i = tid; i < 512; i += 256)
        emb8[i >> 6][i & 63] = state_emb[(size_t)(sbase + (i >> 6)) * 64 + (i & 63)];
    __syncthreads();
    float acc1[8], acc2[8];
#pragma unroll
    for (int s = 0; s < 8; s++) { acc1[s] = 0.f; acc2[s] = 0.f; }
    for (int k = 0; k < 64; k++) {
        float wa = w1[(size_t)k * HID + tid];
        float wb = w1[(size_t)(64 + k) * HID + tid];
#pragma unroll
        for (int s = 0; s < 8; s++) {
            acc1[s] += emb8[s][k] * wa;
            acc2[s] += emb8[s][k] * wb;
        }
    }
#pragma unroll
    for (int s = 0; s < 8; s++) {
        P1[(size_t)(sbase + s) * HID + tid] = acc1[s];
        P2[(size_t)(sbase + s) * HID + tid] = acc2[s];
    }
}

// ---------- relS = bf16( relu(P1[subj]+P2[obj]+b1) @ w2 + b2 ) via MFMA ----------
__global__ __launch_bounds__(256) void k_rel2(
    const int* __restrict__ subjS, const int* __restrict__ objS,
    const float* __restrict__ P1, const float* __restrict__ P2,
    const float* __restrict__ b1, const unsigned short* __restrict__ w2t,
    const float* __restrict__ b2, unsigned short* __restrict__ relS) {
    __shared__ unsigned short h[128][264];
    int tid = threadIdx.x, lane = tid & 63, w = tid >> 6;
    int rbase = blockIdx.x * 128;
    for (int e = tid; e < 128 * 64; e += 256) {
        int r = e >> 6, jc = (e & 63) * 4;
        int subj = subjS[rbase + r], obj = objS[rbase + r];
        float4 p1 = *(const float4*)&P1[(size_t)subj * HID + jc];
        float4 p2 = *(const float4*)&P2[(size_t)obj * HID + jc];
        float4 bv = *(const float4*)&b1[jc];
        ushort4 hv;
        hv.x = f2bf(fmaxf(p1.x + p2.x + bv.x, 0.f));
        hv.y = f2bf(fmaxf(p1.y + p2.y + bv.y, 0.f));
        hv.z = f2bf(fmaxf(p1.z + p2.z + bv.z, 0.f));
        hv.w = f2bf(fmaxf(p1.w + p2.w + bv.w, 0.f));
        *(ushort4*)&h[r][jc] = hv;
    }
    __syncthreads();
    int lr = lane & 15, lh = lane >> 4;
    f32x4 acc[2][4];
#pragma unroll
    for (int rt = 0; rt < 2; rt++)
#pragma unroll
        for (int ct = 0; ct < 4; ct++) acc[rt][ct] = (f32x4){0.f, 0.f, 0.f, 0.f};
#pragma unroll
    for (int kk = 0; kk < 8; kk++) {
        bf16x8 bfr[4], afr[2];
#pragma unroll
        for (int ct = 0; ct < 4; ct++)
            bfr[ct] = *(const bf16x8*)(w2t + (ct * 16 + lr) * 256 + kk * 32 + lh * 8);
#pragma unroll
        for (int rt = 0; rt < 2; rt++)
            afr[rt] = *(const bf16x8*)&h[w * 32 + rt * 16 + lr][kk * 32 + lh * 8];
#pragma unroll
        for (int rt = 0; rt < 2; rt++)
#pragma unroll
            for (int ct = 0; ct < 4; ct++)
                acc[rt][ct] = __builtin_amdgcn_mfma_f32_16x16x32_bf16(
                    afr[rt], bfr[ct], acc[rt][ct], 0, 0, 0);
    }
    float b2v[4];
#pragma unroll
    for (int ct = 0; ct < 4; ct++) b2v[ct] = b2[ct * 16 + lr];
#pragma unroll
    for (int rt = 0; rt < 2; rt++)
#pragma unroll
        for (int ct = 0; ct < 4; ct++)
#pragma unroll
            for (int rg = 0; rg < 4; rg++) {
                int row = rbase + w * 32 + rt * 16 + lh * 4 + rg;
                relS[(size_t)row * 64 + ct * 16 + lr] =
                    f2bf(acc[rt][ct][rg] + b2v[ct]);
            }
}

// ---------- meta chain: 1024 threads, small reg arrays ----------
__global__ __launch_bounds__(1024) void k_meta(
    const int* __restrict__ x, const float* __restrict__ action_emb,
    const float* __restrict__ pos_emb, const float* __restrict__ q_w,
    const float* __restrict__ q_b, const float* __restrict__ ms_w1,
    const float* __restrict__ ms_b1, const float* __restrict__ ms_w2,
    const float* __restrict__ ms_b2, const float* __restrict__ meta_init,
    unsigned short* __restrict__ metas_bf) {
    __shared__ float sent[L][132];
    __shared__ float qs[A][17];
    __shared__ float qb_lds[L];
    __shared__ float meta_lds[A];
    __shared__ float logits_lds[L];
    __shared__ float attn_lds[L];
    __shared__ float hidden_lds[HID];
    __shared__ float parts[16][65];
    __shared__ float b2_lds[A];
    int tid = threadIdx.x;
    int b = blockIdx.x;
    int lane = tid & 63, wv = tid >> 6;

    for (int i = tid; i < L * 128; i += 1024) {
        int l = i >> 7, d = i & 127;
        float v;
        if (d < 64)
            v = action_emb[x[b * XCOLS + SIZE + l] * 64 + d];
        else
            v = pos_emb[l * 64 + (d - 64)];
        sent[l][d] = v;
    }
    if (tid < A) {
        meta_lds[tid] = meta_init[tid];
        b2_lds[tid] = ms_b2[tid];
    }
    __syncthreads();

    {
        int k = tid >> 4, l = tid & 15;
        float a = 0.f;
        for (int j = 0; j < 128; j++) a += q_w[(size_t)k * 128 + j] * sent[l][j];
        qs[k][l] = a;
    }
    if (tid < L) {
        float a = 0.f;
        for (int j = 0; j < 128; j++) a += q_b[j] * sent[tid][j];
        qb_lds[tid] = a;
    }
    int j_h = tid >> 2, q_h = tid & 3;
    float w1a_r[16];
#pragma unroll
    for (int i = 0; i < 16; i++)
        w1a_r[i] = ms_w1[(size_t)(q_h * 16 + i) * HID + j_h];
    float sentw_r[4];
#pragma unroll
    for (int i = 0; i < 4; i++) sentw_r[i] = 0.f;
    for (int d = 0; d < 128; d++) {
        float w = ms_w1[(size_t)(64 + d) * HID + j_h];
#pragma unroll
        for (int i = 0; i < 4; i++) sentw_r[i] += sent[q_h * 4 + i][d] * w;
    }
    float b1_r = ms_b1[j_h];
    int g_m = tid >> 6, c_m = tid & 63;
    float w2_r[16];
#pragma unroll
    for (int i = 0; i < 16; i++)
        w2_r[i] = ms_w2[(size_t)(g_m * 16 + i) * 64 + c_m];
    __syncthreads();

    for (int t = 0; t < L; t++) {
        float p = meta_lds[lane] * qs[lane][wv];
        p += __shfl_xor(p, 32);
        p += __shfl_xor(p, 16);
        p += __shfl_xor(p, 8);
        p += __shfl_xor(p, 4);
        p += __shfl_xor(p, 2);
        p += __shfl_xor(p, 1);
        if (lane == 0) logits_lds[wv] = p + qb_lds[wv];
        __syncthreads();
        if (tid < L) {
            float mx = logits_lds[0];
#pragma unroll
            for (int l = 1; l < L; l++) mx = fmaxf(mx, logits_lds[l]);
            float sum = 0.f;
#pragma unroll
            for (int l = 0; l < L; l++) sum += __expf(logits_lds[l] - mx);
            attn_lds[tid] = __expf(logits_lds[tid] - mx) / sum;
        }
        __syncthreads();
        float h = 0.f;
#pragma unroll
        for (int i = 0; i < 16; i++) h += meta_lds[q_h * 16 + i] * w1a_r[i];
#pragma unroll
        for (int i = 0; i < 4; i++) h += attn_lds[q_h * 4 + i] * sentw_r[i];
        h += __shfl_xor(h, 1);
        h += __shfl_xor(h, 2);
        if (q_h == 0) hidden_lds[j_h] = fmaxf(h + b1_r, 0.f);
        __syncthreads();
        float pp = 0.f;
#pragma unroll
        for (int i = 0; i < 16; i++) pp += hidden_lds[g_m * 16 + i] * w2_r[i];
        parts[g_m][c_m] = pp;
        __syncthreads();
        if (tid < A) {
            float nm = b2_lds[tid];
#pragma unroll
            for (int g = 0; g < 16; g++) nm += parts[g][tid];
            meta_lds[tid] = nm;
            metas_bf[((size_t)t * B + b) * A + tid] = f2bf(nm);
        }
        __syncthreads();
    }
}

// ---------- state step: MFMA dot; masks precomputed off the flush chain ----------
__global__ __launch_bounds__(256) void k_step(
    const int* __restrict__ off, const int* __restrict__ subjS,
    const int* __restrict__ objS, const unsigned short* __restrict__ relS,
    const unsigned short* __restrict__ mb, const float* __restrict__ st_in,
    float* __restrict__ st_out) {
    __shared__ float vals[RPB][66];
    int tid = threadIdx.x, lane = tid & 63, w = tid >> 6;
    int rbase = blockIdx.x * RPB;
    int base_w = rbase + w * 32;
    int lr = lane & 15, lh = lane >> 4;

    // fragment loads first: MFMA waits only on these
    bf16x8 bfrag[4][2];
#pragma unroll
    for (int ct = 0; ct < 4; ct++)
#pragma unroll
        for (int kk = 0; kk < 2; kk++)
            bfrag[ct][kk] =
                *(const bf16x8*)(mb + (ct * 16 + lr) * 64 + kk * 32 + lh * 8);
    bf16x8 afrag[2][2];
#pragma unroll
    for (int rt = 0; rt < 2; rt++)
#pragma unroll
        for (int kk = 0; kk < 2; kk++)
            afrag[rt][kk] = *(const bf16x8*)(relS +
                (size_t)(rbase + w * 32 + rt * 16 + lr) * 64 + kk * 32 + lh * 8);

    // gathers + obj ids issue behind fragments; consumed after MFMA
    float sv[32];
    int ob[32];
#pragma unroll
    for (int rr = 0; rr < 32; rr++) {
        sv[rr] = st_in[(size_t)subjS[base_w + rr] * B + lane];
        ob[rr] = objS[base_w + rr];
    }

    f32x4 acc[2][4];
#pragma unroll
    for (int rt = 0; rt < 2; rt++)
#pragma unroll
        for (int ct = 0; ct < 4; ct++) {
            f32x4 c = {0.f, 0.f, 0.f, 0.f};
            c = __builtin_amdgcn_mfma_f32_16x16x32_bf16(afrag[rt][0],
                                                        bfrag[ct][0], c, 0, 0, 0);
            c = __builtin_amdgcn_mfma_f32_16x16x32_bf16(afrag[rt][1],
                                                        bfrag[ct][1], c, 0, 0, 0);
            acc[rt][ct] = c;
        }

    // segmentation masks: off[] loads overlap MFMA, not the flush chain
    unsigned mnew = 0, mcont = 0;
    {
        int obprev = -1;
#pragma unroll
        for (int rr = 0; rr < 32; rr++) {
            int o = ob[rr];
            if (o != obprev) {
                mnew |= 1u << rr;
                if (off[o] >= base_w && off[o + 1] <= base_w + 32)
                    mcont |= 1u << rr;
            }
            obprev = o;
        }
    }

#pragma unroll
    for (int rt = 0; rt < 2; rt++)
#pragma unroll
        for (int ct = 0; ct < 4; ct++)
#pragma unroll
            for (int rg = 0; rg < 4; rg++) {
                int r_loc = w * 32 + rt * 16 + lh * 4 + rg;
                int c = ct * 16 + lr;
                vals[r_loc][c] = 1.f / (1.f + __expf(-acc[rt][ct][rg]));
            }
    __syncthreads();

    // flush: pure LDS + FMA + stores (no global loads)
    float acc_s = 0.f;
    int curr = 0;
#pragma unroll
    for (int rr = 0; rr < 32; rr++) {
        if (rr > 0 && ((mnew >> rr) & 1u)) {
            int o = ob[curr];
            if ((mcont >> curr) & 1u)
                st_out[(size_t)o * B + lane] = acc_s;
            else
                atomicAdd(&st_out[(size_t)o * B + lane], acc_s);
            acc_s = 0.f;
            curr = rr;
        }
        acc_s += vals[w * 32 + rr][lane] * sv[rr];
    }
    {
        int o = ob[curr];
        if ((mcont >> curr) & 1u)
            st_out[(size_t)o * B + lane] = acc_s;
        else
            atomicAdd(&st_out[(size_t)o * B + lane], acc_s);
    }
}

// ---------- final transpose ----------
__global__ __launch_bounds__(256) void k_out(const float* __restrict__ ST,
                                             float* __restrict__ out) {
    __shared__ float tile[64][65];
    int t = blockIdx.x >> 5;
    int s0 = (blockIdx.x & 31) * 64;
    const float* src = ST + (size_t)(t + 1) * SIZE * B;
    int tid = threadIdx.x;
    for (int i = tid; i < 64 * 64; i += 256) {
        int si = i >> 6, b = i & 63;
        tile[si][b] = src[(size_t)(s0 + si) * B + b];
    }
    __syncthreads();
    for (int i = tid; i < 64 * 64; i += 256) {
        int b = i >> 6, si = i & 63;
        out[((size_t)b * L + t) * SIZE + s0 + si] = tile[si][b];
    }
}

extern "C" void kernel_launch(void* const* d_in, const int* in_sizes, int n_in,
                              void* d_out, int out_size, void* d_ws,
                              size_t ws_size, hipStream_t stream) {
    const int* x = (const int*)d_in[0];
    const int* rel_subj = (const int*)d_in[1];
    const int* rel_obj = (const int*)d_in[2];
    const float* action_emb = (const float*)d_in[3];
    const float* pos_emb = (const float*)d_in[4];
    const float* state_emb = (const float*)d_in[5];
    const float* s2r_w1 = (const float*)d_in[6];
    const float* s2r_b1 = (const float*)d_in[7];
    const float* s2r_w2 = (const float*)d_in[8];
    const float* s2r_b2 = (const float*)d_in[9];
    const float* q_w = (const float*)d_in[10];
    const float* q_b = (const float*)d_in[11];
    const float* ms_w1 = (const float*)d_in[12];
    const float* ms_b1 = (const float*)d_in[13];
    const float* ms_w2 = (const float*)d_in[14];
    const float* ms_b2 = (const float*)d_in[15];
    const float* meta_init = (const float*)d_in[16];

    float* ws = (float*)d_ws;
    float* ST = ws;
    unsigned short* relS = (unsigned short*)(ws + ST_ELEMS);
    unsigned short* metas_bf = relS + (size_t)R_N * 64;
    float* P1 = (float*)(metas_bf + (size_t)L * B * A);
    float* P2 = P1 + SIZE * HID;
    int* ibase = (int*)(P2 + SIZE * HID);
    int* hist = ibase;
    int* off = ibase + 2048;
    int* cursor = off + 2049;
    int* subjS = cursor + 2048;
    int* objS = subjS + R_N;
    unsigned short* w2t = (unsigned short*)d_out;  // overwritten by k_out
    float* out = (float*)d_out;

    k_init<<<256, 256, 0, stream>>>(x, ST, hist, cursor);
    k_hist<<<64, 256, 0, stream>>>(rel_obj, hist);
    k_scan<<<2, 256, 0, stream>>>(hist, off, s2r_w2, w2t);
    k_scatter<<<64, 256, 0, stream>>>(rel_subj, rel_obj, off, cursor, subjS, objS);
    k_p12<<<SIZE / 8, 256, 0, stream>>>(state_emb, s2r_w1, P1, P2);
    k_rel2<<<R_N / RPB, 256, 0, stream>>>(subjS, objS, P1, P2, s2r_b1, w2t,
                                          s2r_b2, relS);
    k_meta<<<B, 1024, 0, stream>>>(x, action_emb, pos_emb, q_w, q_b, ms_w1,
                                   ms_b1, ms_w2, ms_b2, meta_init, metas_bf);
    for (int t = 0; t < L; t++) {
        k_step<<<R_N / RPB, 256, 0, stream>>>(
            off, subjS, objS, relS, metas_bf + (size_t)t * B * A,
            ST + (size_t)t * SIZE * B, ST + (size_t)(t + 1) * SIZE * B);
    }
    k_out<<<512, 256, 0, stream>>>(ST, out);
}